// Round 12
// baseline (130.379 us; speedup 1.0000x reference)
//
#include <hip/hip_runtime.h>

#define T_LEN 512
#define B_SZ  256
#define N_ST  128

#if defined(__has_builtin)
# if __has_builtin(__builtin_amdgcn_fdot2_f32_bf16)
#  define HAVE_DOT2 1
# endif
#endif
#ifndef HAVE_DOT2
# define HAVE_DOT2 0
#endif

typedef unsigned int u32;
typedef short s8v __attribute__((ext_vector_type(8)));   // 8 bf16 (MFMA A/B frag)
typedef float f4v __attribute__((ext_vector_type(4)));   // MFMA C/D frag
typedef __bf16 bf16x2 __attribute__((ext_vector_type(2)));

__device__ __forceinline__ u32 bf16rn(float f) {
    u32 u = __builtin_bit_cast(u32, f);
    u += 0x7fffu + ((u >> 16) & 1u);
    return u >> 16;
}
__device__ __forceinline__ u32 pack2(float lo, float hi) {
    return bf16rn(lo) | (bf16rn(hi) << 16);
}
__device__ __forceinline__ u32 cvtpk(float lo, float hi) {
    u32 r;
    asm("v_cvt_pk_bf16_f32 %0, %1, %2" : "=v"(r) : "v"(lo), "v"(hi));
    return r;
}
__device__ __forceinline__ float dot2b(u32 a, u32 b, float c) {
#if HAVE_DOT2
    return __builtin_amdgcn_fdot2_f32_bf16(__builtin_bit_cast(bf16x2, a),
                                           __builtin_bit_cast(bf16x2, b), c, false);
#else
    float alo = __builtin_bit_cast(float, a << 16);
    float ahi = __builtin_bit_cast(float, a & 0xffff0000u);
    float blo = __builtin_bit_cast(float, b << 16);
    float bhi = __builtin_bit_cast(float, b & 0xffff0000u);
    return fmaf(ahi, bhi, fmaf(alo, blo, c));
#endif
}
__device__ __forceinline__ float readlane0(float v) {
    return __builtin_bit_cast(float, (u32)__builtin_amdgcn_readlane(__builtin_bit_cast(int, v), 0));
}

// Raw barrier: order LDS ops only (lgkmcnt), leave global loads in flight.
#define XBARRIER() asm volatile("s_waitcnt lgkmcnt(0)\n\ts_barrier" ::: "memory")

// pi K-permutation (R6, HW-verified absmax 0.0):  k(ks,g,e) = 16*(2*ks + e/4) + 4*g + (e&3)
// makes MFMA D-frag layout == next step's B-frag layout lane-for-lane.

template <bool TR>
__device__ __forceinline__ s8v loadAE(const float* __restrict__ trans, int mt, int ks, int n, int g) {
    const int m = 16 * mt + n;
    uint4 q;
    #define LA(I, DST) { const int e0 = 2*(I), e1 = 2*(I)+1; \
        const int k0 = 16*(2*ks + (e0 >> 2)) + 4*g + (e0 & 3); \
        const int k1 = 16*(2*ks + (e1 >> 2)) + 4*g + (e1 & 3); \
        const float f0 = TR ? trans[k0 * N_ST + m] : trans[m * N_ST + k0]; \
        const float f1 = TR ? trans[k1 * N_ST + m] : trans[m * N_ST + k1]; \
        DST = cvtpk(__expf(f0), __expf(f1)); }
    LA(0, q.x) LA(1, q.y) LA(2, q.z) LA(3, q.w)
    #undef LA
    return __builtin_bit_cast(s8v, q);
}

__device__ __forceinline__ uint4 initBv(const float* __restrict__ row,
                                        const float* __restrict__ bias, int g, int ks) {
    uint4 q;
    #define IB(I, DST) { const int e0 = 2*(I), e1 = 2*(I)+1; \
        const int m0 = 16*(2*ks + (e0 >> 2)) + 4*g + (e0 & 3); \
        const int m1 = 16*(2*ks + (e1 >> 2)) + 4*g + (e1 & 3); \
        DST = cvtpk(__expf(bias[m0] + row[m0]), __expf(bias[m1] + row[m1])); }
    IB(0, q.x) IB(1, q.y) IB(2, q.z) IB(3, q.w)
    #undef IB
    return q;
}

// ws (floats): [0..255] logZ | [256..511] score | [512..767] lens(int) |
// [768..1023] MaccF | [1024..1279] MaccB | [1280..17663] U (uint4) | [17664..34047] Z (uint4)
#define WS_NEED_BYTES (34048 * 4)

__global__ __launch_bounds__(64) void lengths_kernel(const unsigned char* __restrict__ mask_raw,
                                                     int* __restrict__ lens) {
    int b = blockIdx.x;
    int l = threadIdx.x;
    unsigned char b1 = mask_raw[1], b2 = mask_raw[2];
    int mode = (b1 != 0) ? 0 : ((b2 != 0) ? 2 : 1);
    int cnt = 0;
    if (mode == 0) {
        #pragma unroll
        for (int k = 0; k < 8; ++k) cnt += (mask_raw[(l * 8 + k) * B_SZ + b] != 0);
    } else if (mode == 1) {
        const int* m = (const int*)mask_raw;
        #pragma unroll
        for (int k = 0; k < 8; ++k) cnt += (m[(l * 8 + k) * B_SZ + b] != 0);
    } else {
        const float* m = (const float*)mask_raw;
        #pragma unroll
        for (int k = 0; k < 8; ++k) cnt += (m[(l * 8 + k) * B_SZ + b] != 0.0f);
    }
    #pragma unroll
    for (int off = 1; off < 64; off <<= 1) cnt += __shfl_xor(cnt, off);
    if (l == 0) lens[b] = cnt;
}

#define MCHAIN(DST, A0_, A1_, A2_, A3_) { \
    const f4v z_ = {0.f, 0.f, 0.f, 0.f}; \
    DST = __builtin_amdgcn_mfma_f32_16x16x32_bf16(A0_, B0, z_, 0, 0, 0); \
    DST = __builtin_amdgcn_mfma_f32_16x16x32_bf16(A1_, B1, DST, 0, 0, 0); \
    DST = __builtin_amdgcn_mfma_f32_16x16x32_bf16(A2_, B2, DST, 0, 0, 0); \
    DST = __builtin_amdgcn_mfma_f32_16x16x32_bf16(A3_, B3, DST, 0, 0, 0); }

// Blocks 0..15: forward tiles; 16..31: backward tiles. 4 waves/block, wave w owns
// m-tiles {2w, 2w+1}. amdgpu_waves_per_eu(1,1): R10/R11 allocated VGPR=72 against
// a ~106-reg live set (launch_bounds min-occupancy let the heuristic target ~7
// waves/EU) -> per-step scratch reloads on the serial chain. Demand ~106 is
// below the ~144 attribute ceiling seen in R7, so (1,1) should fit it spill-free.
__global__ void __attribute__((amdgpu_flat_work_group_size(256, 256), amdgpu_waves_per_eu(1, 1)))
fb_kernel(
        const float* __restrict__ emit,
        const float* __restrict__ trans,
        const float* __restrict__ strans,
        const float* __restrict__ etrans,
        const int* __restrict__ lens,
        float* __restrict__ wsMF, float* __restrict__ wsMB,
        uint4* __restrict__ wsU, uint4* __restrict__ wsZ) {
    const int isF = (blockIdx.x < 16);
    const int tl  = isF ? blockIdx.x : (blockIdx.x - 16);
    const int tid = threadIdx.x;
    const int w = tid >> 6, l = tid & 63, g = l >> 4, n = l & 15;
    const int bn = tl * 16 + n;

    __shared__ uint4 xch[2][4][64];
    __shared__ float dsh[2][16];

    const size_t TS = (size_t)B_SZ * N_ST;
    const int len_n = lens[bn];
    const int m_n = (len_n - 2 < 255) ? (len_n - 2) : 255;   // meet index
    const float* eeb = emit + (size_t)bn * N_ST + 32 * w + 4 * g;  // EE gather base

    s8v B0, B1, B2, B3;
    uint4 my;
    float Macc = 0.f, sclog = 0.f, inv = 1.0f;
    int pp = 0;
    f4v LBa, LBb, LCa, LCb, EEa, EEb;

    if (isF) {
        // ---------------- FORWARD ----------------
        const s8v Aa0 = loadAE<true>(trans, 2 * w,     0, n, g);
        const s8v Aa1 = loadAE<true>(trans, 2 * w,     1, n, g);
        const s8v Aa2 = loadAE<true>(trans, 2 * w,     2, n, g);
        const s8v Aa3 = loadAE<true>(trans, 2 * w,     3, n, g);
        const s8v Ab0 = loadAE<true>(trans, 2 * w + 1, 0, n, g);
        const s8v Ab1 = loadAE<true>(trans, 2 * w + 1, 1, n, g);
        const s8v Ab2 = loadAE<true>(trans, 2 * w + 1, 2, n, g);
        const s8v Ab3 = loadAE<true>(trans, 2 * w + 1, 3, n, g);

        int tmax = m_n;
        #pragma unroll
        for (int off = 1; off < 16; off <<= 1) tmax = max(tmax, __shfl_xor(tmax, off));

        const float* e0 = emit + (size_t)bn * N_ST;
        const uint4 b0 = initBv(e0, strans, g, 0);
        const uint4 b1 = initBv(e0, strans, g, 1);
        const uint4 b2 = initBv(e0, strans, g, 2);
        const uint4 b3 = initBv(e0, strans, g, 3);
        B0 = __builtin_bit_cast(s8v, b0);  B1 = __builtin_bit_cast(s8v, b1);
        B2 = __builtin_bit_cast(s8v, b2);  B3 = __builtin_bit_cast(s8v, b3);
        my = (w == 0) ? b0 : (w == 1) ? b1 : (w == 2) ? b2 : b3;

        LBa = *(const f4v*)(eeb + TS);       LBb = *(const f4v*)(eeb + 16 + TS);
        EEa = f4v{__expf(LBa.x), __expf(LBa.y), __expf(LBa.z), __expf(LBa.w)};
        EEb = f4v{__expf(LBb.x), __expf(LBb.y), __expf(LBb.z), __expf(LBb.w)};
        {
            const size_t t2 = (size_t)((2 <= tmax) ? 2 : tmax) * TS;
            LBa = *(const f4v*)(eeb + t2);   LBb = *(const f4v*)(eeb + 16 + t2);
        }
        // EE holds exp(emit[1]); LB holds emit[2]

        for (int t = 1; t <= tmax; ++t) {
            const size_t tp = (size_t)((t + 2 <= tmax) ? t + 2 : tmax) * TS;
            LCa = *(const f4v*)(eeb + tp);   LCb = *(const f4v*)(eeb + 16 + tp);
            const bool cond = (t <= m_n);
            Macc += cond ? sclog : 0.0f;
            f4v Da, Db;
            MCHAIN(Da, Aa0, Aa1, Aa2, Aa3)
            MCHAIN(Db, Ab0, Ab1, Ab2, Ab3)
            if (w == 0 && l < 16) dsh[pp][l] = Da.x;     // raw r[state0][batch l]
            const f4v sa = Da * EEa, sb = Db * EEb;
            uint4 nw;
            nw.x = cvtpk(sa.x, sa.y);  nw.y = cvtpk(sa.z, sa.w);
            nw.z = cvtpk(sb.x, sb.y);  nw.w = cvtpk(sb.z, sb.w);
            my.x = cond ? nw.x : my.x;  my.y = cond ? nw.y : my.y;
            my.z = cond ? nw.z : my.z;  my.w = cond ? nw.w : my.w;
            xch[pp][w][l] = my;
            XBARRIER();                                  // lgkm-only drain; vmem stays in flight
            B0 = __builtin_bit_cast(s8v, xch[pp][0][l]);
            B1 = __builtin_bit_cast(s8v, xch[pp][1][l]);
            B2 = __builtin_bit_cast(s8v, xch[pp][2][l]);
            B3 = __builtin_bit_cast(s8v, xch[pp][3][l]);
            const float d00 = dsh[pp][n];
            inv = __builtin_amdgcn_rcpf(d00);
            sclog = -__logf(inv);
            EEa = f4v{__expf(LBa.x), __expf(LBa.y), __expf(LBa.z), __expf(LBa.w)} * inv;
            EEb = f4v{__expf(LBb.x), __expf(LBb.y), __expf(LBb.z), __expf(LBb.w)} * inv;
            LBa = LCa; LBb = LCb;
            pp ^= 1;
        }
        // u = E^T a_m (unscaled extra pass), stored bf16-packed in B-word format
        f4v Da, Db;
        MCHAIN(Da, Aa0, Aa1, Aa2, Aa3)
        MCHAIN(Db, Ab0, Ab1, Ab2, Ab3)
        uint4 uw;
        uw.x = cvtpk(Da.x, Da.y);  uw.y = cvtpk(Da.z, Da.w);
        uw.z = cvtpk(Db.x, Db.y);  uw.w = cvtpk(Db.z, Db.w);
        wsU[(tl * 4 + w) * 64 + l] = uw;
        if (w == 0 && l < 16) wsMF[tl * 16 + l] = Macc;
    } else {
        // ---------------- BACKWARD ----------------
        const s8v Aa0 = loadAE<false>(trans, 2 * w,     0, n, g);
        const s8v Aa1 = loadAE<false>(trans, 2 * w,     1, n, g);
        const s8v Aa2 = loadAE<false>(trans, 2 * w,     2, n, g);
        const s8v Aa3 = loadAE<false>(trans, 2 * w,     3, n, g);
        const s8v Ab0 = loadAE<false>(trans, 2 * w + 1, 0, n, g);
        const s8v Ab1 = loadAE<false>(trans, 2 * w + 1, 1, n, g);
        const s8v Ab2 = loadAE<false>(trans, 2 * w + 1, 2, n, g);
        const s8v Ab3 = loadAE<false>(trans, 2 * w + 1, 3, n, g);

        int smax = len_n - 1, smin = m_n + 1;
        #pragma unroll
        for (int off = 1; off < 16; off <<= 1) {
            smax = max(smax, __shfl_xor(smax, off));
            smin = min(smin, __shfl_xor(smin, off));
        }
        const uint4 Zi = initBv(emit + (size_t)(len_n - 1) * TS + (size_t)bn * N_ST, etrans, g, w);
        const uint4 z4 = {0u, 0u, 0u, 0u};
        B0 = __builtin_bit_cast(s8v, z4);  B1 = B0;  B2 = B0;  B3 = B0;
        my = z4;

        LBa = *(const f4v*)(eeb + (size_t)smax * TS);
        LBb = *(const f4v*)(eeb + 16 + (size_t)smax * TS);
        EEa = f4v{__expf(LBa.x), __expf(LBa.y), __expf(LBa.z), __expf(LBa.w)};
        EEb = f4v{__expf(LBb.x), __expf(LBb.y), __expf(LBb.z), __expf(LBb.w)};
        {
            const size_t s1 = (size_t)((smax - 1 >= smin) ? smax - 1 : smin) * TS;
            LBa = *(const f4v*)(eeb + s1);   LBb = *(const f4v*)(eeb + 16 + s1);
        }

        for (int s = smax; s >= smin; --s) {
            const size_t sp = (size_t)((s - 2 >= smin) ? s - 2 : smin) * TS;
            LCa = *(const f4v*)(eeb + sp);   LCb = *(const f4v*)(eeb + 16 + sp);
            const bool condS = (s >= m_n + 1) && (s <= len_n - 2);
            const bool condI = (s == len_n - 1);
            Macc += condS ? sclog : 0.0f;
            f4v Da, Db;
            MCHAIN(Da, Aa0, Aa1, Aa2, Aa3)
            MCHAIN(Db, Ab0, Ab1, Ab2, Ab3)
            if (w == 0 && l < 16) dsh[pp][l] = Da.x;
            const f4v sa = Da * EEa, sb = Db * EEb;
            uint4 nw;
            nw.x = cvtpk(sa.x, sa.y);  nw.y = cvtpk(sa.z, sa.w);
            nw.z = cvtpk(sb.x, sb.y);  nw.w = cvtpk(sb.z, sb.w);
            my.x = condI ? Zi.x : (condS ? nw.x : my.x);
            my.y = condI ? Zi.y : (condS ? nw.y : my.y);
            my.z = condI ? Zi.z : (condS ? nw.z : my.z);
            my.w = condI ? Zi.w : (condS ? nw.w : my.w);
            xch[pp][w][l] = my;
            XBARRIER();                                  // lgkm-only drain
            B0 = __builtin_bit_cast(s8v, xch[pp][0][l]);
            B1 = __builtin_bit_cast(s8v, xch[pp][1][l]);
            B2 = __builtin_bit_cast(s8v, xch[pp][2][l]);
            B3 = __builtin_bit_cast(s8v, xch[pp][3][l]);
            const float d00 = dsh[pp][n];
            inv = (d00 > 0.0f) ? __builtin_amdgcn_rcpf(d00) : 1.0f;
            sclog = -__logf(inv);
            EEa = f4v{__expf(LBa.x), __expf(LBa.y), __expf(LBa.z), __expf(LBa.w)} * inv;
            EEb = f4v{__expf(LBb.x), __expf(LBb.y), __expf(LBb.z), __expf(LBb.w)} * inv;
            LBa = LCa; LBb = LCb;
            pp ^= 1;
        }
        wsZ[(tl * 4 + w) * 64 + l] = my;      // z_{m+1}, bf16 B-word format
        if (w == 0 && l < 16) wsMB[tl * 16 + l] = Macc;
    }
}

__global__ __launch_bounds__(256) void combine_kernel(
        const uint4* __restrict__ wsU, const uint4* __restrict__ wsZ,
        const float* __restrict__ wsMF, const float* __restrict__ wsMB,
        float* __restrict__ logZ) {
    const int tl = blockIdx.x;            // 16 tiles
    const int tid = threadIdx.x;
    const int w = tid >> 6, l = tid & 63, n = l & 15;
    const uint4 u = wsU[(tl * 4 + w) * 64 + l];
    const uint4 z = wsZ[(tl * 4 + w) * 64 + l];
    float v = 0.f;
    v = dot2b(u.x, z.x, v);  v = dot2b(u.y, z.y, v);
    v = dot2b(u.z, z.z, v);  v = dot2b(u.w, z.w, v);
    __shared__ float red[16][17];
    red[n][w * 4 + (l >> 4)] = v;
    __syncthreads();
    if (tid < 16) {
        float s = 0.f;
        #pragma unroll
        for (int i = 0; i < 16; ++i) s += red[tid][i];
        logZ[tl * 16 + tid] = wsMF[tl * 16 + tid] + wsMB[tl * 16 + tid] + __logf(s);
    }
}

// ---------------- R9 fallback forward (proven): used if ws too small ----------------
__global__ __launch_bounds__(128, 1) void forward_fallback(
        const float* __restrict__ emit, const float* __restrict__ trans,
        const float* __restrict__ strans, const float* __restrict__ etrans,
        const int* __restrict__ lens, float* __restrict__ logZ_out) {
    const int b = blockIdx.x;
    const int tid = threadIdx.x;
    const int wid = tid >> 6;
    const int l = tid & 63;
    const int c0 = 2 * l, c1 = 2 * l + 1;
    __shared__ alignas(16) u32 a32[64];
    __shared__ alignas(16) u32 z32[64];
    __shared__ float meetA[N_ST], meetY[N_ST];
    __shared__ float maccSh[2], red2[2];
    const int len = lens[b];
    const int m = (len - 1 < 256) ? (len - 1) : 256;
    const float* eb = emit + (size_t)b * N_ST;
    const size_t TS = (size_t)B_SZ * N_ST;
    if (wid == 0) {
        u32 EA[64], EB[64];
        #pragma unroll
        for (int p = 0; p < 64; ++p) {
            EA[p] = pack2(__expf(trans[(2 * p) * N_ST + c0]), __expf(trans[(2 * p + 1) * N_ST + c0]));
            EB[p] = pack2(__expf(trans[(2 * p) * N_ST + c1]), __expf(trans[(2 * p + 1) * N_ST + c1]));
        }
        float aA = __expf(strans[c0] + eb[c0]);
        float aB = __expf(strans[c1] + eb[c1]);
        a32[l] = pack2(aA, aB);
        float Macc = 0.f, inv = 1.0f;
        float ec0 = eb[TS + c0], ec1 = eb[TS + c1];
        float en0 = eb[2 * TS + c0], en1 = eb[2 * TS + c1];
        for (int t = 1; t <= m; ++t) {
            const size_t t2 = (size_t)((t + 2 <= m) ? t + 2 : m) * TS;
            const float e20 = eb[t2 + c0], e21 = eb[t2 + c1];
            const float ee0 = __expf(ec0), ee1 = __expf(ec1);
            float A0 = 0, A1 = 0, A2 = 0, A3 = 0, Bb0 = 0, Bb1 = 0, Bb2 = 0, Bb3 = 0;
            #pragma unroll
            for (int q = 0; q < 16; ++q) {
                uint4 ww;
                __builtin_memcpy(&ww, (const char*)a32 + 16 * q, 16);
                A0 = dot2b(ww.x, EA[4 * q + 0], A0);  Bb0 = dot2b(ww.x, EB[4 * q + 0], Bb0);
                A1 = dot2b(ww.y, EA[4 * q + 1], A1);  Bb1 = dot2b(ww.y, EB[4 * q + 1], Bb1);
                A2 = dot2b(ww.z, EA[4 * q + 2], A2);  Bb2 = dot2b(ww.z, EB[4 * q + 2], Bb2);
                A3 = dot2b(ww.w, EA[4 * q + 3], A3);  Bb3 = dot2b(ww.w, EB[4 * q + 3], Bb3);
            }
            const float rA = (A0 + A1) + (A2 + A3);
            const float rB = (Bb0 + Bb1) + (Bb2 + Bb3);
            Macc -= __logf(inv);
            aA = ee0 * rA * inv;  aB = ee1 * rB * inv;
            a32[l] = cvtpk(aA, aB);
            inv = __builtin_amdgcn_rcpf(readlane0(rA));
            ec0 = en0; ec1 = en1; en0 = e20; en1 = e21;
        }
        meetA[c0] = aA; meetA[c1] = aB;
        if (l == 0) maccSh[0] = Macc;
    } else {
        u32 RA[64], RB[64];
        #pragma unroll
        for (int p = 0; p < 64; ++p) {
            RA[p] = pack2(__expf(trans[c0 * N_ST + 2 * p]), __expf(trans[c0 * N_ST + 2 * p + 1]));
            RB[p] = pack2(__expf(trans[c1 * N_ST + 2 * p]), __expf(trans[c1 * N_ST + 2 * p + 1]));
        }
        float y0 = __expf(etrans[c0]);
        float y1 = __expf(etrans[c1]);
        float Maccb = 0.f, invb = 1.0f;
        const int t0 = len - 1;
        float ec0 = eb[(size_t)t0 * TS + c0], ec1 = eb[(size_t)t0 * TS + c1];
        float en0 = ec0, en1 = ec1;
        if (t0 - 1 > m) { en0 = eb[(size_t)(t0 - 1) * TS + c0]; en1 = eb[(size_t)(t0 - 1) * TS + c1]; }
        for (int t = t0; t > m; --t) {
            const int tp = (t - 2 > m) ? t - 2 : m + 1;
            const float e20 = eb[(size_t)tp * TS + c0], e21 = eb[(size_t)tp * TS + c1];
            const float ee0 = __expf(ec0), ee1 = __expf(ec1);
            z32[l] = cvtpk(ee0 * y0, ee1 * y1);
            float R0 = 0, R1 = 0, R2 = 0, R3 = 0, S0 = 0, S1 = 0, S2 = 0, S3 = 0;
            #pragma unroll
            for (int q = 0; q < 16; ++q) {
                uint4 ww;
                __builtin_memcpy(&ww, (const char*)z32 + 16 * q, 16);
                R0 = dot2b(ww.x, RA[4 * q + 0], R0);  S0 = dot2b(ww.x, RB[4 * q + 0], S0);
                R1 = dot2b(ww.y, RA[4 * q + 1], R1);  S1 = dot2b(ww.y, RB[4 * q + 1], S1);
                R2 = dot2b(ww.z, RA[4 * q + 2], R2);  S2 = dot2b(ww.z, RB[4 * q + 2], S2);
                R3 = dot2b(ww.w, RA[4 * q + 3], R3);  S3 = dot2b(ww.w, RB[4 * q + 3], S3);
            }
            const float rR = (R0 + R1) + (R2 + R3);
            const float rS = (S0 + S1) + (S2 + S3);
            Maccb -= __logf(invb);
            y0 = rR * invb;  y1 = rS * invb;
            invb = __builtin_amdgcn_rcpf(readlane0(rR));
            ec0 = en0; ec1 = en1; en0 = e20; en1 = e21;
        }
        meetY[c0] = y0; meetY[c1] = y1;
        if (l == 0) maccSh[1] = Maccb;
    }
    __syncthreads();
    float v = meetA[tid] * meetY[tid];
    #pragma unroll
    for (int off = 1; off < 64; off <<= 1) v += __shfl_xor(v, off);
    if (l == 0) red2[wid] = v;
    __syncthreads();
    if (tid == 0) logZ_out[b] = maccSh[0] + maccSh[1] + __logf(red2[0] + red2[1]);
}

__global__ __launch_bounds__(128) void score_kernel(
        const float* __restrict__ emit,
        const int* __restrict__ target,
        const float* __restrict__ trans,
        const float* __restrict__ strans,
        const float* __restrict__ etrans,
        const int* __restrict__ lens,
        float* __restrict__ score_out) {
    const int b = blockIdx.x;
    const int tid = threadIdx.x;
    const int len = lens[b];
    float local = 0.f;
    for (int t = tid; t < len; t += 128) {
        int tgt = target[t * B_SZ + b];
        float v = emit[(size_t)t * (B_SZ * N_ST) + b * N_ST + tgt];
        if (t > 0) v += trans[target[(t - 1) * B_SZ + b] * N_ST + tgt];
        local += v;
    }
    if (tid == 0) {
        local += strans[target[b]];
        local += etrans[target[(len - 1) * B_SZ + b]];
    }
    #pragma unroll
    for (int off = 1; off < 64; off <<= 1) local += __shfl_xor(local, off);
    __shared__ float partial[2];
    if ((tid & 63) == 0) partial[tid >> 6] = local;
    __syncthreads();
    if (tid == 0) score_out[b] = partial[0] + partial[1];
}

__global__ __launch_bounds__(256) void finalize_kernel(
        const float* __restrict__ logZ,
        const float* __restrict__ score,
        float* __restrict__ out) {
    int tid = threadIdx.x;
    float v = logZ[tid] - score[tid];
    #pragma unroll
    for (int off = 1; off < 64; off <<= 1) v += __shfl_xor(v, off);
    __shared__ float p[4];
    if ((tid & 63) == 0) p[tid >> 6] = v;
    __syncthreads();
    if (tid == 0) out[0] = (p[0] + p[1] + p[2] + p[3]) / 256.0f;
}

extern "C" void kernel_launch(void* const* d_in, const int* in_sizes, int n_in,
                              void* d_out, int out_size, void* d_ws, size_t ws_size,
                              hipStream_t stream) {
    const float*         emit   = (const float*)d_in[0];
    const int*           target = (const int*)d_in[1];
    const unsigned char* mask   = (const unsigned char*)d_in[2];
    const float*         trans  = (const float*)d_in[3];
    const float*         strans = (const float*)d_in[4];
    const float*         etrans = (const float*)d_in[5];

    float* ws     = (float*)d_ws;
    float* logZb  = ws;                 // 256
    float* scoreb = ws + 256;           // 256
    int*   lens   = (int*)(ws + 512);   // 256
    float* wsMF   = ws + 768;           // 256
    float* wsMB   = ws + 1024;          // 256
    uint4* wsU    = (uint4*)(ws + 1280);    // 4096 uint4
    uint4* wsZ    = (uint4*)(ws + 17664);   // 4096 uint4

    lengths_kernel<<<B_SZ, 64, 0, stream>>>(mask, lens);
    if (ws_size >= (size_t)WS_NEED_BYTES) {
        fb_kernel<<<32, 256, 0, stream>>>(emit, trans, strans, etrans, lens, wsMF, wsMB, wsU, wsZ);
        combine_kernel<<<16, 256, 0, stream>>>(wsU, wsZ, wsMF, wsMB, logZb);
    } else {
        forward_fallback<<<B_SZ, 128, 0, stream>>>(emit, trans, strans, etrans, lens, logZb);
    }
    score_kernel<<<B_SZ, 128, 0, stream>>>(emit, target, trans, strans, etrans, lens, scoreb);
    finalize_kernel<<<1, 256, 0, stream>>>(logZb, scoreb, (float*)d_out);
}

// Round 13
// 125.827 us; speedup vs baseline: 1.0362x; 1.0362x over previous
//
#include <hip/hip_runtime.h>

#define T_LEN 512
#define B_SZ  256
#define N_ST  128

#if defined(__has_builtin)
# if __has_builtin(__builtin_amdgcn_fdot2_f32_bf16)
#  define HAVE_DOT2 1
# endif
#endif
#ifndef HAVE_DOT2
# define HAVE_DOT2 0
#endif

typedef unsigned int uint32;
typedef __bf16 bf16x2 __attribute__((ext_vector_type(2)));

__device__ __forceinline__ uint32 bf16rn(float f) {   // RNE bf16 (no NaNs here)
    uint32 u = __builtin_bit_cast(uint32, f);
    u += 0x7fffu + ((u >> 16) & 1u);
    return u >> 16;
}
__device__ __forceinline__ uint32 pack2(float lo, float hi) {
    return bf16rn(lo) | (bf16rn(hi) << 16);
}
__device__ __forceinline__ uint32 cvtpk(float lo, float hi) {   // HW packed cvt, RNE
    uint32 r;
    asm("v_cvt_pk_bf16_f32 %0, %1, %2" : "=v"(r) : "v"(lo), "v"(hi));
    return r;
}
__device__ __forceinline__ float readlane0(float v) {   // lane 0 -> SGPR (NOT the DS pipe)
    return __builtin_bit_cast(float, (uint32)__builtin_amdgcn_readlane(__builtin_bit_cast(int, v), 0));
}
__device__ __forceinline__ float dot2b(uint32 a, uint32 b, float c) {
#if HAVE_DOT2
    return __builtin_amdgcn_fdot2_f32_bf16(__builtin_bit_cast(bf16x2, a),
                                           __builtin_bit_cast(bf16x2, b), c, false);
#else
    float alo = __builtin_bit_cast(float, a << 16);
    float ahi = __builtin_bit_cast(float, a & 0xffff0000u);
    float blo = __builtin_bit_cast(float, b << 16);
    float bhi = __builtin_bit_cast(float, b & 0xffff0000u);
    return fmaf(ahi, bhi, fmaf(alo, blo, c));
#endif
}

// ws layout (floats): [0..255] logZ_b ; [256..511] score_b ; [512..767] lens (int)

__global__ __launch_bounds__(64) void lengths_kernel(const unsigned char* __restrict__ mask_raw,
                                                     int* __restrict__ lens) {
    int b = blockIdx.x;   // 256 blocks
    int l = threadIdx.x;  // 64 threads
    // Detect mask encoding (mask[0][*] always true since lengths >= T/2):
    // u8: byte[1]=1 ; i32: bytes1,2=0 ; f32: 1.0f -> byte[2]=0x80
    unsigned char b1 = mask_raw[1], b2 = mask_raw[2];
    int mode = (b1 != 0) ? 0 : ((b2 != 0) ? 2 : 1);
    int cnt = 0;
    if (mode == 0) {
        #pragma unroll
        for (int k = 0; k < 8; ++k) cnt += (mask_raw[(l * 8 + k) * B_SZ + b] != 0);
    } else if (mode == 1) {
        const int* m = (const int*)mask_raw;
        #pragma unroll
        for (int k = 0; k < 8; ++k) cnt += (m[(l * 8 + k) * B_SZ + b] != 0);
    } else {
        const float* m = (const float*)mask_raw;
        #pragma unroll
        for (int k = 0; k < 8; ++k) cnt += (m[(l * 8 + k) * B_SZ + b] != 0.0f);
    }
    #pragma unroll
    for (int off = 1; off < 64; off <<= 1) cnt += __shfl_xor(cnt, off);
    if (l == 0) lens[b] = cnt;
}

// Meet-in-the-middle CRF forward: logZ = log <a_m, y_m>.
//   wave 0: a_t = ee_t o (E^T a_{t-1}),  t = 1..m        (E columns)
//   wave 1: y_{t-1} = E (ee_t o y_t),    t = len-1..m+1  (E rows)
// m = min(256, len-1). R9 structure verbatim; the ONE change vs R9:
// amdgpu_waves_per_eu(1,1) -- R9's VGPR=140 vs ~152-reg live set means ~12
// E-registers spilled and reloaded per step on the serial chain. R12 proved
// the attribute raises the granted budget; demand 152 should now fit.
__global__ void __attribute__((amdgpu_flat_work_group_size(128, 128), amdgpu_waves_per_eu(1, 1)))
forward_kernel(
        const float* __restrict__ emit,
        const float* __restrict__ trans,
        const float* __restrict__ strans,
        const float* __restrict__ etrans,
        const int* __restrict__ lens,
        float* __restrict__ logZ_out) {
    const int b   = blockIdx.x;
    const int tid = threadIdx.x;      // 0..127
    const int wid = tid >> 6;         // 0 = forward, 1 = backward
    const int l   = tid & 63;
    const int c0  = 2 * l, c1 = 2 * l + 1;   // owned cols (fwd) / rows (bwd)

    __shared__ alignas(16) uint32 a32[64];   // fwd a-vector, bf16x2 packed
    __shared__ alignas(16) uint32 z32[64];   // bwd ee*y vector, bf16x2 packed
    __shared__ float meetA[N_ST], meetY[N_ST];
    __shared__ float maccSh[2], red2[2];

    const int len = lens[b];
    const int m = (len - 1 < 256) ? (len - 1) : 256;
    const float* eb = emit + (size_t)b * N_ST;
    const size_t TS = (size_t)B_SZ * N_ST;

    if (wid == 0) {
        // ---- forward: E columns c0, c1 packed over i-pairs ----
        uint32 EA[64], EB[64];
        #pragma unroll
        for (int p = 0; p < 64; ++p) {
            EA[p] = pack2(__expf(trans[(2 * p) * N_ST + c0]), __expf(trans[(2 * p + 1) * N_ST + c0]));
            EB[p] = pack2(__expf(trans[(2 * p) * N_ST + c1]), __expf(trans[(2 * p + 1) * N_ST + c1]));
        }
        float aA = __expf(strans[c0] + eb[c0]);
        float aB = __expf(strans[c1] + eb[c1]);
        a32[l] = pack2(aA, aB);
        float Macc = 0.f, inv = 1.0f;
        // 2-deep emit pipeline: ec = emit[t], en = emit[t+1]
        float ec0 = eb[TS + c0],      ec1 = eb[TS + c1];        // emit[1]
        float en0 = eb[2 * TS + c0],  en1 = eb[2 * TS + c1];    // emit[2] (len>=256)
        for (int t = 1; t <= m; ++t) {
            const size_t t2 = (size_t)((t + 2 <= m) ? t + 2 : m) * TS;
            const float e20 = eb[t2 + c0], e21 = eb[t2 + c1];   // prefetch, 2 iters ahead
            const float ee0 = __expf(ec0), ee1 = __expf(ec1);
            float A0 = 0, A1 = 0, A2 = 0, A3 = 0, B0 = 0, B1 = 0, B2 = 0, B3 = 0;
            #pragma unroll
            for (int q = 0; q < 16; ++q) {
                uint4 w;  // alias-safe broadcast LDS read
                __builtin_memcpy(&w, (const char*)a32 + 16 * q, 16);
                A0 = dot2b(w.x, EA[4 * q + 0], A0);  B0 = dot2b(w.x, EB[4 * q + 0], B0);
                A1 = dot2b(w.y, EA[4 * q + 1], A1);  B1 = dot2b(w.y, EB[4 * q + 1], B1);
                A2 = dot2b(w.z, EA[4 * q + 2], A2);  B2 = dot2b(w.z, EB[4 * q + 2], B2);
                A3 = dot2b(w.w, EA[4 * q + 3], A3);  B3 = dot2b(w.w, EB[4 * q + 3], B3);
            }
            const float rA = (A0 + A1) + (A2 + A3);
            const float rB = (B0 + B1) + (B2 + B3);
            Macc -= __logf(inv);                       // bookkeeping (off write path)
            aA = ee0 * rA * inv;                       // delayed uniform normalizer
            aB = ee1 * rB * inv;
            a32[l] = cvtpk(aA, aB);                    // ONE ds_write_b32
            inv = __builtin_amdgcn_rcpf(readlane0(rA));  // scalar path, NOT DS pipe
            ec0 = en0; ec1 = en1; en0 = e20; en1 = e21;
        }
        meetA[c0] = aA; meetA[c1] = aB;
        if (l == 0) maccSh[0] = Macc;
    } else {
        // ---- backward: E rows c0, c1 packed over j-pairs (contiguous trans reads) ----
        uint32 RA[64], RB[64];
        #pragma unroll
        for (int p = 0; p < 64; ++p) {
            RA[p] = pack2(__expf(trans[c0 * N_ST + 2 * p]), __expf(trans[c0 * N_ST + 2 * p + 1]));
            RB[p] = pack2(__expf(trans[c1 * N_ST + 2 * p]), __expf(trans[c1 * N_ST + 2 * p + 1]));
        }
        float y0 = __expf(etrans[c0]);                 // y_{len-1} = exp(etrans)
        float y1 = __expf(etrans[c1]);
        float Maccb = 0.f, invb = 1.0f;
        const int t0 = len - 1;
        float ec0 = eb[(size_t)t0 * TS + c0], ec1 = eb[(size_t)t0 * TS + c1];
        float en0 = ec0, en1 = ec1;
        if (t0 - 1 > m) { en0 = eb[(size_t)(t0 - 1) * TS + c0]; en1 = eb[(size_t)(t0 - 1) * TS + c1]; }
        for (int t = t0; t > m; --t) {
            const int tp = (t - 2 > m) ? t - 2 : m + 1;
            const float e20 = eb[(size_t)tp * TS + c0], e21 = eb[(size_t)tp * TS + c1];
            const float ee0 = __expf(ec0), ee1 = __expf(ec1);
            z32[l] = cvtpk(ee0 * y0, ee1 * y1);        // z = ee_t o y_t ; ONE write
            float R0 = 0, R1 = 0, R2 = 0, R3 = 0, S0 = 0, S1 = 0, S2 = 0, S3 = 0;
            #pragma unroll
            for (int q = 0; q < 16; ++q) {
                uint4 w;
                __builtin_memcpy(&w, (const char*)z32 + 16 * q, 16);
                R0 = dot2b(w.x, RA[4 * q + 0], R0);  S0 = dot2b(w.x, RB[4 * q + 0], S0);
                R1 = dot2b(w.y, RA[4 * q + 1], R1);  S1 = dot2b(w.y, RB[4 * q + 1], S1);
                R2 = dot2b(w.z, RA[4 * q + 2], R2);  S2 = dot2b(w.z, RB[4 * q + 2], S2);
                R3 = dot2b(w.w, RA[4 * q + 3], R3);  S3 = dot2b(w.w, RB[4 * q + 3], S3);
            }
            const float rR = (R0 + R1) + (R2 + R3);
            const float rS = (S0 + S1) + (S2 + S3);
            Maccb -= __logf(invb);
            y0 = rR * invb;                            // delayed normalizer, mirrored
            y1 = rS * invb;
            invb = __builtin_amdgcn_rcpf(readlane0(rR));
            ec0 = en0; ec1 = en1; en0 = e20; en1 = e21;
        }
        meetY[c0] = y0; meetY[c1] = y1;
        if (l == 0) maccSh[1] = Maccb;
    }

    // ---- meet: logZ = MaccF + MaccB + log( sum_j a_m[j] * y_m[j] ) ----
    __syncthreads();
    float v = meetA[tid] * meetY[tid];
    #pragma unroll
    for (int off = 1; off < 64; off <<= 1) v += __shfl_xor(v, off);
    if (l == 0) red2[wid] = v;
    __syncthreads();
    if (tid == 0) logZ_out[b] = maccSh[0] + maccSh[1] + __logf(red2[0] + red2[1]);
}

__global__ __launch_bounds__(128) void score_kernel(
        const float* __restrict__ emit,
        const int* __restrict__ target,
        const float* __restrict__ trans,
        const float* __restrict__ strans,
        const float* __restrict__ etrans,
        const int* __restrict__ lens,
        float* __restrict__ score_out) {
    const int b   = blockIdx.x;
    const int tid = threadIdx.x;  // 128
    const int len = lens[b];
    float local = 0.f;
    for (int t = tid; t < len; t += 128) {
        int tgt = target[t * B_SZ + b];
        float v = emit[(size_t)t * (B_SZ * N_ST) + b * N_ST + tgt];
        if (t > 0) v += trans[target[(t - 1) * B_SZ + b] * N_ST + tgt];
        local += v;
    }
    if (tid == 0) {
        local += strans[target[b]];
        local += etrans[target[(len - 1) * B_SZ + b]];
    }
    #pragma unroll
    for (int off = 1; off < 64; off <<= 1) local += __shfl_xor(local, off);
    __shared__ float partial[2];
    if ((tid & 63) == 0) partial[tid >> 6] = local;
    __syncthreads();
    if (tid == 0) score_out[b] = partial[0] + partial[1];
}

__global__ __launch_bounds__(256) void finalize_kernel(
        const float* __restrict__ logZ,
        const float* __restrict__ score,
        float* __restrict__ out) {
    int tid = threadIdx.x;  // 256
    float v = logZ[tid] - score[tid];
    #pragma unroll
    for (int off = 1; off < 64; off <<= 1) v += __shfl_xor(v, off);
    __shared__ float p[4];
    if ((tid & 63) == 0) p[tid >> 6] = v;
    __syncthreads();
    if (tid == 0) out[0] = (p[0] + p[1] + p[2] + p[3]) / 256.0f;
}

extern "C" void kernel_launch(void* const* d_in, const int* in_sizes, int n_in,
                              void* d_out, int out_size, void* d_ws, size_t ws_size,
                              hipStream_t stream) {
    const float*         emit   = (const float*)d_in[0];
    const int*           target = (const int*)d_in[1];
    const unsigned char* mask   = (const unsigned char*)d_in[2];
    const float*         trans  = (const float*)d_in[3];
    const float*         strans = (const float*)d_in[4];
    const float*         etrans = (const float*)d_in[5];

    float* ws     = (float*)d_ws;
    float* logZb  = ws;            // 256
    float* scoreb = ws + 256;      // 256
    int*   lens   = (int*)(ws + 512);

    lengths_kernel<<<B_SZ, 64, 0, stream>>>(mask, lens);
    forward_kernel<<<B_SZ, 128, 0, stream>>>(emit, trans, strans, etrans, lens, logZb);
    score_kernel<<<B_SZ, 128, 0, stream>>>(emit, target, trans, strans, etrans, lens, scoreb);
    finalize_kernel<<<1, 256, 0, stream>>>(logZb, scoreb, (float*)d_out);
}

// Round 14
// 123.160 us; speedup vs baseline: 1.0586x; 1.0216x over previous
//
#include <hip/hip_runtime.h>

#define T_LEN 512
#define B_SZ  256
#define N_ST  128

#if defined(__has_builtin)
# if __has_builtin(__builtin_amdgcn_fdot2_f32_bf16)
#  define HAVE_DOT2 1
# endif
#endif
#ifndef HAVE_DOT2
# define HAVE_DOT2 0
#endif

typedef unsigned int uint32;
typedef __bf16 bf16x2 __attribute__((ext_vector_type(2)));
typedef float f2v __attribute__((ext_vector_type(2)));
typedef uint4 __attribute__((may_alias)) uint4a;   // alias-safe LDS vector read (forces ds_read_b128)

__device__ __forceinline__ uint32 bf16rn(float f) {   // RNE bf16 (no NaNs here)
    uint32 u = __builtin_bit_cast(uint32, f);
    u += 0x7fffu + ((u >> 16) & 1u);
    return u >> 16;
}
__device__ __forceinline__ uint32 pack2(float lo, float hi) {
    return bf16rn(lo) | (bf16rn(hi) << 16);
}
__device__ __forceinline__ uint32 cvtpk(float lo, float hi) {   // HW packed cvt, RNE
    uint32 r;
    asm("v_cvt_pk_bf16_f32 %0, %1, %2" : "=v"(r) : "v"(lo), "v"(hi));
    return r;
}
__device__ __forceinline__ float readlane0(float v) {   // lane 0 -> SGPR (NOT the DS pipe)
    return __builtin_bit_cast(float, (uint32)__builtin_amdgcn_readlane(__builtin_bit_cast(int, v), 0));
}
__device__ __forceinline__ float dot2b(uint32 a, uint32 b, float c) {
#if HAVE_DOT2
    return __builtin_amdgcn_fdot2_f32_bf16(__builtin_bit_cast(bf16x2, a),
                                           __builtin_bit_cast(bf16x2, b), c, false);
#else
    float alo = __builtin_bit_cast(float, a << 16);
    float ahi = __builtin_bit_cast(float, a & 0xffff0000u);
    float blo = __builtin_bit_cast(float, b << 16);
    float bhi = __builtin_bit_cast(float, b & 0xffff0000u);
    return fmaf(ahi, bhi, fmaf(alo, blo, c));
#endif
}

// ws layout (floats): [0..255] logZ_b ; [256..511] score_b ; [512..767] lens (int)

__global__ __launch_bounds__(64) void lengths_kernel(const unsigned char* __restrict__ mask_raw,
                                                     int* __restrict__ lens) {
    int b = blockIdx.x;   // 256 blocks
    int l = threadIdx.x;  // 64 threads
    // Detect mask encoding (mask[0][*] always true since lengths >= T/2):
    // u8: byte[1]=1 ; i32: bytes1,2=0 ; f32: 1.0f -> byte[2]=0x80
    unsigned char b1 = mask_raw[1], b2 = mask_raw[2];
    int mode = (b1 != 0) ? 0 : ((b2 != 0) ? 2 : 1);
    int cnt = 0;
    if (mode == 0) {
        #pragma unroll
        for (int k = 0; k < 8; ++k) cnt += (mask_raw[(l * 8 + k) * B_SZ + b] != 0);
    } else if (mode == 1) {
        const int* m = (const int*)mask_raw;
        #pragma unroll
        for (int k = 0; k < 8; ++k) cnt += (m[(l * 8 + k) * B_SZ + b] != 0);
    } else {
        const float* m = (const float*)mask_raw;
        #pragma unroll
        for (int k = 0; k < 8; ++k) cnt += (m[(l * 8 + k) * B_SZ + b] != 0.0f);
    }
    #pragma unroll
    for (int off = 1; off < 64; off <<= 1) cnt += __shfl_xor(cnt, off);
    if (l == 0) lens[b] = cnt;
}

// Meet-in-the-middle CRF forward: logZ = log <a_m, y_m>.
//   wave 0: a_t = ee_t o (E^T a_{t-1}),  t = 1..m        (E columns)
//   wave 1: y_{t-1} = E (ee_t o y_t),    t = len-1..m+1  (E rows)
// m = min(256, len-1). vs R13 (two mechanical changes only):
//  - LDS reads via may_alias uint4 (guaranteed ds_read_b128; memcpy may scalarize)
//  - 4-deep emit pipeline of float2 loads (1 dwordx2/step, ~5400 cyc slack)
__global__ void __attribute__((amdgpu_flat_work_group_size(128, 128), amdgpu_waves_per_eu(1, 1)))
forward_kernel(
        const float* __restrict__ emit,
        const float* __restrict__ trans,
        const float* __restrict__ strans,
        const float* __restrict__ etrans,
        const int* __restrict__ lens,
        float* __restrict__ logZ_out) {
    const int b   = blockIdx.x;
    const int tid = threadIdx.x;      // 0..127
    const int wid = tid >> 6;         // 0 = forward, 1 = backward
    const int l   = tid & 63;
    const int c0  = 2 * l, c1 = 2 * l + 1;   // owned cols (fwd) / rows (bwd)

    __shared__ alignas(16) uint32 a32[64];   // fwd a-vector, bf16x2 packed
    __shared__ alignas(16) uint32 z32[64];   // bwd ee*y vector, bf16x2 packed
    __shared__ float meetA[N_ST], meetY[N_ST];
    __shared__ float maccSh[2], red2[2];

    const int len = lens[b];
    const int m = (len - 1 < 256) ? (len - 1) : 256;
    const float* eb = emit + (size_t)b * N_ST;
    const size_t TS2 = (size_t)B_SZ * N_ST / 2;            // float2 stride per t
    const f2v* ebv = (const f2v*)eb;                        // lane reads ebv[t*TS2 + l]

    if (wid == 0) {
        // ---- forward: E columns c0, c1 packed over i-pairs ----
        uint32 EA[64], EB[64];
        #pragma unroll
        for (int p = 0; p < 64; ++p) {
            EA[p] = pack2(__expf(trans[(2 * p) * N_ST + c0]), __expf(trans[(2 * p + 1) * N_ST + c0]));
            EB[p] = pack2(__expf(trans[(2 * p) * N_ST + c1]), __expf(trans[(2 * p + 1) * N_ST + c1]));
        }
        float aA = __expf(strans[c0] + eb[c0]);
        float aB = __expf(strans[c1] + eb[c1]);
        a32[l] = pack2(aA, aB);
        float Macc = 0.f, inv = 1.0f;
        // 4-deep emit pipeline (consume emit[t] at step t; m >= 255 so 1..4 valid)
        #define EIDX(T) ((size_t)(((T) <= m) ? (T) : m) * TS2 + l)
        f2v p0 = ebv[EIDX(1)];
        f2v p1 = ebv[EIDX(2)];
        f2v p2 = ebv[EIDX(3)];
        f2v p3 = ebv[EIDX(4)];
        for (int t = 1; t <= m; ++t) {
            const f2v pn = ebv[EIDX(t + 4)];               // prefetch, 4 iters ahead
            const float ee0 = __expf(p0.x), ee1 = __expf(p0.y);
            float A0 = 0, A1 = 0, A2 = 0, A3 = 0, B0 = 0, B1 = 0, B2 = 0, B3 = 0;
            const uint4a* aw = (const uint4a*)a32;
            #pragma unroll
            for (int q = 0; q < 16; ++q) {
                const uint4 w = aw[q];                     // ds_read_b128 broadcast
                A0 = dot2b(w.x, EA[4 * q + 0], A0);  B0 = dot2b(w.x, EB[4 * q + 0], B0);
                A1 = dot2b(w.y, EA[4 * q + 1], A1);  B1 = dot2b(w.y, EB[4 * q + 1], B1);
                A2 = dot2b(w.z, EA[4 * q + 2], A2);  B2 = dot2b(w.z, EB[4 * q + 2], B2);
                A3 = dot2b(w.w, EA[4 * q + 3], A3);  B3 = dot2b(w.w, EB[4 * q + 3], B3);
            }
            const float rA = (A0 + A1) + (A2 + A3);
            const float rB = (B0 + B1) + (B2 + B3);
            Macc -= __logf(inv);                           // bookkeeping (off write path)
            aA = ee0 * rA * inv;                           // delayed uniform normalizer
            aB = ee1 * rB * inv;
            a32[l] = cvtpk(aA, aB);                        // ONE ds_write_b32
            inv = __builtin_amdgcn_rcpf(readlane0(rA));    // scalar path, NOT DS pipe
            p0 = p1; p1 = p2; p2 = p3; p3 = pn;
        }
        #undef EIDX
        meetA[c0] = aA; meetA[c1] = aB;
        if (l == 0) maccSh[0] = Macc;
    } else {
        // ---- backward: E rows c0, c1 packed over j-pairs (contiguous trans reads) ----
        uint32 RA[64], RB[64];
        #pragma unroll
        for (int p = 0; p < 64; ++p) {
            RA[p] = pack2(__expf(trans[c0 * N_ST + 2 * p]), __expf(trans[c0 * N_ST + 2 * p + 1]));
            RB[p] = pack2(__expf(trans[c1 * N_ST + 2 * p]), __expf(trans[c1 * N_ST + 2 * p + 1]));
        }
        float y0 = __expf(etrans[c0]);                     // y_{len-1} = exp(etrans)
        float y1 = __expf(etrans[c1]);
        float Maccb = 0.f, invb = 1.0f;
        const int t0 = len - 1;
        // 4-deep pipeline, descending t; clamp to m+1 (<= 257 < T_LEN, always in bounds)
        #define EIDXB(T) ((size_t)(((T) > m) ? (T) : (m + 1)) * TS2 + l)
        f2v p0 = ebv[EIDXB(t0)];
        f2v p1 = ebv[EIDXB(t0 - 1)];
        f2v p2 = ebv[EIDXB(t0 - 2)];
        f2v p3 = ebv[EIDXB(t0 - 3)];
        for (int t = t0; t > m; --t) {
            const f2v pn = ebv[EIDXB(t - 4)];              // prefetch, 4 iters ahead
            const float ee0 = __expf(p0.x), ee1 = __expf(p0.y);
            z32[l] = cvtpk(ee0 * y0, ee1 * y1);            // z = ee_t o y_t ; ONE write
            float R0 = 0, R1 = 0, R2 = 0, R3 = 0, S0 = 0, S1 = 0, S2 = 0, S3 = 0;
            const uint4a* zw = (const uint4a*)z32;
            #pragma unroll
            for (int q = 0; q < 16; ++q) {
                const uint4 w = zw[q];                     // ds_read_b128 broadcast
                R0 = dot2b(w.x, RA[4 * q + 0], R0);  S0 = dot2b(w.x, RB[4 * q + 0], S0);
                R1 = dot2b(w.y, RA[4 * q + 1], R1);  S1 = dot2b(w.y, RB[4 * q + 1], S1);
                R2 = dot2b(w.z, RA[4 * q + 2], R2);  S2 = dot2b(w.z, RB[4 * q + 2], S2);
                R3 = dot2b(w.w, RA[4 * q + 3], R3);  S3 = dot2b(w.w, RB[4 * q + 3], S3);
            }
            const float rR = (R0 + R1) + (R2 + R3);
            const float rS = (S0 + S1) + (S2 + S3);
            Maccb -= __logf(invb);
            y0 = rR * invb;                                // delayed normalizer, mirrored
            y1 = rS * invb;
            invb = __builtin_amdgcn_rcpf(readlane0(rR));
            p0 = p1; p1 = p2; p2 = p3; p3 = pn;
        }
        #undef EIDXB
        meetY[c0] = y0; meetY[c1] = y1;
        if (l == 0) maccSh[1] = Maccb;
    }

    // ---- meet: logZ = MaccF + MaccB + log( sum_j a_m[j] * y_m[j] ) ----
    __syncthreads();
    float v = meetA[tid] * meetY[tid];
    #pragma unroll
    for (int off = 1; off < 64; off <<= 1) v += __shfl_xor(v, off);
    if (l == 0) red2[wid] = v;
    __syncthreads();
    if (tid == 0) logZ_out[b] = maccSh[0] + maccSh[1] + __logf(red2[0] + red2[1]);
}

__global__ __launch_bounds__(128) void score_kernel(
        const float* __restrict__ emit,
        const int* __restrict__ target,
        const float* __restrict__ trans,
        const float* __restrict__ strans,
        const float* __restrict__ etrans,
        const int* __restrict__ lens,
        float* __restrict__ score_out) {
    const int b   = blockIdx.x;
    const int tid = threadIdx.x;  // 128
    const int len = lens[b];
    float local = 0.f;
    for (int t = tid; t < len; t += 128) {
        int tgt = target[t * B_SZ + b];
        float v = emit[(size_t)t * (B_SZ * N_ST) + b * N_ST + tgt];
        if (t > 0) v += trans[target[(t - 1) * B_SZ + b] * N_ST + tgt];
        local += v;
    }
    if (tid == 0) {
        local += strans[target[b]];
        local += etrans[target[(len - 1) * B_SZ + b]];
    }
    #pragma unroll
    for (int off = 1; off < 64; off <<= 1) local += __shfl_xor(local, off);
    __shared__ float partial[2];
    if ((tid & 63) == 0) partial[tid >> 6] = local;
    __syncthreads();
    if (tid == 0) score_out[b] = partial[0] + partial[1];
}

__global__ __launch_bounds__(256) void finalize_kernel(
        const float* __restrict__ logZ,
        const float* __restrict__ score,
        float* __restrict__ out) {
    int tid = threadIdx.x;  // 256
    float v = logZ[tid] - score[tid];
    #pragma unroll
    for (int off = 1; off < 64; off <<= 1) v += __shfl_xor(v, off);
    __shared__ float p[4];
    if ((tid & 63) == 0) p[tid >> 6] = v;
    __syncthreads();
    if (tid == 0) out[0] = (p[0] + p[1] + p[2] + p[3]) / 256.0f;
}

extern "C" void kernel_launch(void* const* d_in, const int* in_sizes, int n_in,
                              void* d_out, int out_size, void* d_ws, size_t ws_size,
                              hipStream_t stream) {
    const float*         emit   = (const float*)d_in[0];
    const int*           target = (const int*)d_in[1];
    const unsigned char* mask   = (const unsigned char*)d_in[2];
    const float*         trans  = (const float*)d_in[3];
    const float*         strans = (const float*)d_in[4];
    const float*         etrans = (const float*)d_in[5];

    float* ws     = (float*)d_ws;
    float* logZb  = ws;            // 256
    float* scoreb = ws + 256;      // 256
    int*   lens   = (int*)(ws + 512);

    lengths_kernel<<<B_SZ, 64, 0, stream>>>(mask, lens);
    forward_kernel<<<B_SZ, 128, 0, stream>>>(emit, trans, strans, etrans, lens, logZb);
    score_kernel<<<B_SZ, 128, 0, stream>>>(emit, target, trans, strans, etrans, lens, scoreb);
    finalize_kernel<<<1, 256, 0, stream>>>(logZb, scoreb, (float*)d_out);
}